// Round 17
// baseline (1005.532 us; speedup 1.0000x reference)
//
#include <hip/hip_runtime.h>
#include <hip/hip_bf16.h>
#include <math.h>

using bf16 = __hip_bfloat16;
using bf16x8 = __attribute__((ext_vector_type(8))) short;
using f32x4  = __attribute__((ext_vector_type(4))) float;

#define B_ 8
#define H_ 384
#define W_ 512
#define HW_ (H_*W_)
#define H2_ 192
#define W2_ 256
#define H4_ 96
#define W4_ 128

#define TEMP_F 30.0f
#define HARD_Z_F 0.001f
#define EPS_F 1e-6f

// d_out element offsets (float32), in return order
#define O_IT 0
#define O_IW 4718592
#define O_V  9437184
#define O_O  11010048
#define O_GG 12582912
#define O_DG 15728640
#define O_ZT 18874368

// ---- workspace layout (bytes), lifetime-multiplexed ----
#define WS_ZBUF  0
#define WS_ACC   6291456
#define WS_H1    0
#define WS_H2    101582848
#define WS_XIN   203165696
#define WS_E0    0
#define WS_E1    101582848
#define WS_E2    152836096
#define WS_D1    178927616
#define WS_D0H   101582848
#define WS_WT    230180864
#define WS_KINV  230742016
#define WS_ZMAX  230742528

// weight sub-offsets in ELEMENTS within WS_WT (fragment-order, padded K)
#define WT_F1 0
#define WT_F2 3072
#define WT_F3 15360
#define WT_E0 21504
#define WT_E1 24576
#define WT_E2 49152
#define WT_D1 131072
#define WT_D0 245760
#define WT_O  274432

static __device__ __forceinline__ short f2bs(float f){
  __hip_bfloat16 h = __float2bfloat16(f);
  return *reinterpret_cast<short*>(&h);
}

// S-chunk selection shared by wprep and gconv
template<int NSTEP> struct SSel {
  static constexpr int S = (NSTEP > 6) ? 4 : ((NSTEP > 3) ? 2 : 1);
  static constexpr int NSTEPP = ((NSTEP + S - 1)/S)*S;
};

// ================= splat =================
__global__ void k_mats(const float* __restrict__ Ks, float* __restrict__ kinv){
#pragma clang fp contract(off)
  int b = threadIdx.x;
  if (b >= B_) return;
  float A[3][3]; int piv[3] = {0,1,2};
  for (int k=0;k<3;k++) for (int j=0;j<3;j++) A[k][j] = Ks[b*9 + k*3 + j];
  for (int k=0;k<3;k++){
    int p = k; float mx = fabsf(A[k][k]);
    for (int i=k+1;i<3;i++){ float v = fabsf(A[i][k]); if (v > mx){ mx = v; p = i; } }
    if (p != k){
      for (int j=0;j<3;j++){ float t = A[k][j]; A[k][j] = A[p][j]; A[p][j] = t; }
      int t = piv[k]; piv[k] = piv[p]; piv[p] = t;
    }
    for (int i=k+1;i<3;i++){
      A[i][k] = A[i][k] / A[k][k];
      for (int j=k+1;j<3;j++) A[i][j] = A[i][j] - A[i][k]*A[k][j];
    }
  }
  for (int col=0; col<3; col++){
    float y0 = (piv[0]==col) ? 1.0f : 0.0f;
    float y1 = (piv[1]==col) ? 1.0f : 0.0f;
    float y2 = (piv[2]==col) ? 1.0f : 0.0f;
    y1 = y1 - A[1][0]*y0;
    y2 = (y2 - A[2][0]*y0) - A[2][1]*y1;
    float x2 = y2 / A[2][2];
    float x1 = (y1 - A[1][2]*x2) / A[1][1];
    float x0 = ((y0 - A[0][1]*x1) - A[0][2]*x2) / A[0][0];
    kinv[b*9 + 0*3 + col] = x0;
    kinv[b*9 + 1*3 + col] = x1;
    kinv[b*9 + 2*3 + col] = x2;
  }
}

__device__ __forceinline__ void proj_f(const float* __restrict__ Ki,
                                       const float* __restrict__ T,
                                       const float* __restrict__ Q,
                                       float d, float px, float py,
                                       float& xt, float& yt, float& z){
#pragma clang fp contract(off)
  float c0 = ((Ki[0]*px + Ki[1]*py) + Ki[2]) * d;
  float c1 = ((Ki[3]*px + Ki[4]*py) + Ki[5]) * d;
  float c2 = ((Ki[6]*px + Ki[7]*py) + Ki[8]) * d;
  float X0 = ((T[0]*c0 + T[1]*c1) + T[2]*c2) + T[3];
  float X1 = ((T[4]*c0 + T[5]*c1) + T[6]*c2) + T[7];
  float X2 = ((T[8]*c0 + T[9]*c1) + T[10]*c2) + T[11];
  float p0 = (Q[0]*X0 + Q[1]*X1) + Q[2]*X2;
  float p1 = (Q[3]*X0 + Q[4]*X1) + Q[5]*X2;
  float p2 = (Q[6]*X0 + Q[7]*X1) + Q[8]*X2;
  z = p2;
  float zc = fmaxf(z, EPS_F);
  xt = p0/zc; yt = p1/zc;
}

__global__ void k_proj(const float* __restrict__ Ds, const float* __restrict__ Kt,
                       const float* __restrict__ dT, const float* __restrict__ kinv,
                       unsigned* __restrict__ zmax,
                       unsigned* __restrict__ zbuf, float* __restrict__ out){
#pragma clang fp contract(off)
  int pix = blockIdx.x*256 + threadIdx.x;
  int b = blockIdx.y;
  int y = pix / W_, x = pix % W_;
  float d = fmaxf(__builtin_nontemporal_load(Ds + b*HW_ + pix), 0.001f);
  float xv, yv, z;
  proj_f(kinv + b*9, dT + b*16, Kt + b*9, d, (float)x, (float)y, xv, yv, z);
  int gi = b*HW_ + pix;
  __builtin_nontemporal_store((2.0f*xv + 1.0f)/(float)W_ - 1.0f, out + O_GG + 2*gi + 0);
  __builtin_nontemporal_store((2.0f*yv + 1.0f)/(float)H_ - 1.0f, out + O_GG + 2*gi + 1);
  __builtin_nontemporal_store(z, out + O_ZT + gi);
  float zi = (z > EPS_F) ? z : 0.0f;
  #pragma unroll
  for (int off=32; off; off>>=1) zi = fmaxf(zi, __shfl_down(zi, off, 64));
  __shared__ float sm[4];
  int lane = threadIdx.x & 63, wid = threadIdx.x >> 6;
  if (lane==0) sm[wid]=zi;
  __syncthreads();
  if (threadIdx.x==0){
    float m = fmaxf(fmaxf(sm[0],sm[1]), fmaxf(sm[2],sm[3]));
    atomicMax(zmax + b, __float_as_uint(m));
  }
  if (z > EPS_F){
    float x0 = floorf(xv), y0 = floorf(yv);
    unsigned zu = __float_as_uint(z);
    #pragma unroll
    for (int c=0;c<4;c++){
      float cx = x0 + (float)(c&1), cy = y0 + (float)(c>>1);
      float bw = (1.0f - fabsf(xv-cx)) * (1.0f - fabsf(yv-cy));
      if (cx>=0.f && cx<(float)W_ && cy>=0.f && cy<(float)H_ && bw>0.f){
        int flat = b*HW_ + (int)cy*W_ + (int)cx;
        atomicMin(zbuf + flat, zu);
      }
    }
  }
}

// planar acc: [4][B*HW]
__global__ void k_acc(const float* __restrict__ Is, const float* __restrict__ Ds,
                      const float* __restrict__ Kt, const float* __restrict__ dT,
                      const float* __restrict__ kinv,
                      const float* __restrict__ zbuf,
                      const unsigned* __restrict__ zmax,
                      float* __restrict__ acc){
#pragma clang fp contract(off)
  const int NP = B_*HW_;
  int pix = blockIdx.x*256+threadIdx.x;
  int b = blockIdx.y;
  int y = pix / W_, x = pix % W_;
  float d = fmaxf(__builtin_nontemporal_load(Ds + b*HW_ + pix), 0.001f);
  float xv, yv, z;
  proj_f(kinv + b*9, dT + b*16, Kt + b*9, d, (float)x, (float)y, xv, yv, z);
  if (!(z > EPS_F)) return;
  float zm = __uint_as_float(zmax[b]) + EPS_F;
  float q = z / zm;
  float w = expf((-TEMP_F) * q);
  float r  = __builtin_nontemporal_load(Is + (b*3+0)*HW_+pix);
  float g  = __builtin_nontemporal_load(Is + (b*3+1)*HW_+pix);
  float bl = __builtin_nontemporal_load(Is + (b*3+2)*HW_+pix);
  float x0 = floorf(xv), y0 = floorf(yv);
  #pragma unroll
  for (int c=0;c<4;c++){
    float cx = x0 + (float)(c&1), cy = y0 + (float)(c>>1);
    float bw = (1.0f - fabsf(xv-cx)) * (1.0f - fabsf(yv-cy));
    if (cx>=0.f && cx<(float)W_ && cy>=0.f && cy<(float)H_ && bw>0.f){
      int flat = b*HW_ + (int)cy*W_ + (int)cx;
      if (z <= zbuf[flat] + HARD_Z_F){
        float wt = bw*w;
        atomicAdd(acc + flat, wt*r);
        atomicAdd(acc + NP + flat, wt*g);
        atomicAdd(acc + 2*NP + flat, wt*bl);
        atomicAdd(acc + 3*NP + flat, wt);
      }
    }
  }
}

// k_norm + fused flow-net input pack
__global__ void k_norm(const float* __restrict__ acc, const float* __restrict__ Is,
                       const float* __restrict__ Ds, float* __restrict__ out,
                       bf16* __restrict__ xin){
#pragma clang fp contract(off)
  const int NP = B_*HW_;
  int pix = blockIdx.x*256+threadIdx.x;
  int b = blockIdx.y;
  int y = pix / W_, x = pix % W_;
  int gi = b*HW_+pix;
  float nx = __builtin_nontemporal_load(acc + gi);
  float ny = __builtin_nontemporal_load(acc + NP + gi);
  float nz = __builtin_nontemporal_load(acc + 2*NP + gi);
  float den = __builtin_nontemporal_load(acc + 3*NP + gi);
  float denc = fmaxf(den, EPS_F);
  bool on = den > EPS_F;
  float V = fminf(fmaxf(den, 0.0f), 1.0f);
  float i0 = __builtin_nontemporal_load(Is + (b*3+0)*HW_+pix);
  float i1 = __builtin_nontemporal_load(Is + (b*3+1)*HW_+pix);
  float i2 = __builtin_nontemporal_load(Is + (b*3+2)*HW_+pix);
  float dv = __builtin_nontemporal_load(Ds + gi);
  __builtin_nontemporal_store(on ? nx/denc : 0.0f, out + O_IW + (b*3+0)*HW_+pix);
  __builtin_nontemporal_store(on ? ny/denc : 0.0f, out + O_IW + (b*3+1)*HW_+pix);
  __builtin_nontemporal_store(on ? nz/denc : 0.0f, out + O_IW + (b*3+2)*HW_+pix);
  __builtin_nontemporal_store(V, out + O_V + gi);
  bf16x8 v;
  v[0] = f2bs(i0);
  v[1] = f2bs(i1);
  v[2] = f2bs(i2);
  v[3] = f2bs(dv);
  v[4] = f2bs(V);
  v[5] = 0; v[6] = 0; v[7] = 0;
  *reinterpret_cast<bf16x8*>(xin + (((b*(H_+2) + y+1))*(W_+2) + x+1)*8) = v;
}

// halo zeroing: border ring of a padded NHWC/blocked buffer (per 32/8-ch group)
template<int C>
__global__ void k_halo(bf16* __restrict__ buf, int Hp, int Wp, int nb){
  int nh = 2*Wp + 2*(Hp-2);
  int i = blockIdx.x*256 + threadIdx.x;
  int total = nb*nh*(C/8);
  if (i >= total) return;
  int cv = i % (C/8); int hp = (i / (C/8)) % nh; int b = i / ((C/8)*nh);
  int y, x;
  if (hp < Wp){ y = 0; x = hp; }
  else if (hp < 2*Wp){ y = Hp-1; x = hp - Wp; }
  else { int r = hp - 2*Wp; y = 1 + (r>>1); x = (r&1) ? Wp-1 : 0; }
  bf16x8 zv = {0,0,0,0,0,0,0,0};
  *reinterpret_cast<bf16x8*>(buf + (((size_t)b*Hp + y)*Wp + x)*C + cv*8) = zv;
}

// ======== weight repack -> MFMA FRAGMENT ORDER in global memory ========
template<int CIN, int CPAD, int COUT, int CT, int NCO>
__global__ void k_wprep(const float* __restrict__ src, bf16* __restrict__ dst){
  constexpr int KP = ((9*CPAD + 31)/32)*32;
  constexpr int NSTEP = KP/32;
  constexpr int NSTEPP = SSel<NSTEP>::NSTEPP;
  constexpr int NN = CT/16;
  int i = blockIdx.x*256 + threadIdx.x;
  if (i >= NCO*NSTEPP*NN*512) return;
  int e8 = i & 7;
  int g = i >> 3;
  int l = g & 63;
  int rest = g >> 6;
  int n = rest % NN;
  int rest2 = rest / NN;
  int ks = rest2 % NSTEPP;
  int cog = rest2 / NSTEPP;
  int co = cog*CT + n*16 + (l & 15);
  int k = ks*32 + (l >> 4)*8 + e8;
  int tap = k / CPAD, c = k - tap*CPAD;
  float v = 0.0f;
  if (co < COUT && tap < 9 && c < CIN)
    v = src[((co*CIN + c)*3 + tap/3)*3 + (tap%3)];
  dst[i] = __float2bfloat16(v);
}

// ===== MFMA implicit-GEMM 3x3 conv: channel-blocked activations (coalesced A) =====
// Activations with C>32 are stored [b][cg][Hp][Wp][32]; C<=32 is the CG=1 case.
// ACT: 0 = ReLU -> bf16 outP (blocked tiled store); 1 = flow head (+unet pack); 2 = IT head
template<int CPAD, int CA, int STRIDE, int MM, int NN, int ACT, int COUT,
         int GX, int GY, int GZ>
__global__ __launch_bounds__(256) void k_gconv(
    const bf16* __restrict__ inB, const bf16* __restrict__ inA,
    const bf16* __restrict__ wt, const float* __restrict__ bias,
    bf16* __restrict__ outP, float* __restrict__ out2, bf16* __restrict__ xinU,
    int HpB, int WpB, int HpA, int WpA, int HpO, int WpO, int bo2)
{
  constexpr int CB = CPAD - CA;
  constexpr int CGB = (CB >= 32) ? CB/32 : 1;
  constexpr int CGA = (CA >= 32) ? CA/32 : 1;
  constexpr int CGO = (COUT >= 32) ? COUT/32 : 1;
  constexpr int KP = ((9*CPAD + 31)/32)*32;
  constexpr int NSTEP = KP/32;
  constexpr int CT = 16*NN;
  constexpr int NCO = COUT/CT;
  constexpr int S = SSel<NSTEP>::S;
  constexpr int NSTEPP = SSel<NSTEP>::NSTEPP;
  constexpr int FULL = NSTEP / S;
  constexpr int REM  = NSTEP % S;
  constexpr int NGRAN = S*NN*64;
  constexpr int JW = (NGRAN + 255)/256;
  constexpr int PIPES = NGRAN*8;
  constexpr int PXB = 64*MM;
  constexpr int PIPEB = 2*PIPES*2;
  constexpr int TILEB = (ACT==0) ? PXB*CT*2 : 0;
  constexpr int MAXB = (PIPEB > TILEB) ? PIPEB : TILEB;
  __shared__ __align__(16) char smem[MAXB];
  short* ldsS = reinterpret_cast<short*>(smem);

  // XCD-chunked bijective swizzle
  constexpr int NWG = GX*GY*GZ;
  constexpr int Q = NWG/8, R = NWG%8;
  int orig = blockIdx.x;
  int xcd = orig & 7, idx = orig >> 3;
  int wg = (xcd < R ? xcd*(Q+1) : R*(Q+1) + (xcd-R)*Q) + idx;
  int bx = wg % GX;
  int by = (wg / GX) % GY;
  int bz = wg / (GX*GY);

  int lane = threadIdx.x & 63;
  int w = threadIdx.x >> 6;
  int arow = lane & 15, kg = lane >> 4;
  int y = by;
  int b = bz / NCO;
  int co0 = (bz - b*NCO) * CT;
  int px0 = bx*PXB + w*(16*MM);
  int t = threadIdx.x;
  const bf16* wgbase = wt + (size_t)(co0/CT)*NSTEPP*NN*512;

  f32x4 acc[MM][NN];
  #pragma unroll
  for (int m=0;m<MM;m++)
    #pragma unroll
    for (int n=0;n<NN;n++) acc[m][n] = (f32x4){0.f,0.f,0.f,0.f};

  // per-lane invariant offsets for A (blocked: 32ch inner)
  int laneB[MM];
  int lamA[MM][3];
  #pragma unroll
  for (int m=0;m<MM;m++){
    int px = px0 + m*16 + arow;
    laneB[m] = (STRIDE==1 ? px : 2*px)*32 + kg*8;
    if constexpr (CA > 0){
      #pragma unroll
      for (int kx=0;kx<3;kx++)
        lamA[m][kx] = (((px + kx - 1) >> 1) + 1)*32 + kg*8;
    }
  }

  auto LDA = [&](int ks, bf16x8 (&a)[MM]) {
    if constexpr (CPAD >= 32){
      int kk0 = ks*32;
      int tap = kk0 / CPAD;
      int c0 = kk0 - tap*CPAD;
      int kyy = tap/3, kx = tap - kyy*3;
      bool isA = false;
      if constexpr (CA > 0) isA = (c0 < CA);
      if (isA){
        if constexpr (CA > 0){
          int cga = c0 >> 5;
          int yu = ((y + kyy - 1) >> 1) + 1;
          int sA = ((b*CGA + cga)*HpA + yu)*WpA*32;
          #pragma unroll
          for (int m=0;m<MM;m++){
            int la = (kx==0) ? lamA[m][0] : ((kx==1) ? lamA[m][1] : lamA[m][2]);
            a[m] = *reinterpret_cast<const bf16x8*>(inA + sA + la);
          }
        }
      } else {
        int cgb = (c0 - CA) >> 5;
        int sB = (STRIDE==1)
          ? (((b*CGB + cgb)*HpB + y + kyy)*WpB + kx)*32
          : (((b*CGB + cgb)*HpB + 2*y + kyy + 1)*WpB + kx + 1)*32;
        #pragma unroll
        for (int m=0;m<MM;m++)
          a[m] = *reinterpret_cast<const bf16x8*>(inB + sB + laneB[m]);
      }
    } else {
      int k = ks*32 + kg*8;
      int tap = k >> 3;
      if (tap >= 9) tap = 0;
      int kyy = tap/3, kx = tap - (tap/3)*3;
      #pragma unroll
      for (int m=0;m<MM;m++){
        int px = px0 + m*16 + arow;
        a[m] = *reinterpret_cast<const bf16x8*>(inB + ((b*HpB + y + kyy)*WpB + px + kx)*8);
      }
    }
  };

  auto STAGE_LOAD = [&](int p, bf16x8 (&sreg)[JW]){
    const bf16* g = wgbase + (size_t)p*NGRAN*8;
    #pragma unroll
    for (int j=0;j<JW;j++){
      int e = t + j*256;
      if (NGRAN >= 256*(j+1) || e < NGRAN)
        sreg[j] = *reinterpret_cast<const bf16x8*>(g + e*8);
    }
  };
  auto STAGE_WRITE = [&](int buf, bf16x8 (&sreg)[JW]){
    #pragma unroll
    for (int j=0;j<JW;j++){
      int e = t + j*256;
      if (NGRAN >= 256*(j+1) || e < NGRAN)
        *reinterpret_cast<bf16x8*>(&ldsS[buf*PIPES + e*8]) = sreg[j];
    }
  };

  auto COMPUTE = [&](int buf, int s, bf16x8 (&a)[MM]){
    bf16x8 bb[NN];
    #pragma unroll
    for (int n=0;n<NN;n++)
      bb[n] = *reinterpret_cast<const bf16x8*>(&ldsS[buf*PIPES + ((s*NN + n)*64 + lane)*8]);
    #pragma unroll
    for (int m=0;m<MM;m++)
      #pragma unroll
      for (int n=0;n<NN;n++)
        acc[m][n] = __builtin_amdgcn_mfma_f32_16x16x32_bf16(a[m], bb[n], acc[m][n], 0,0,0);
  };

  bf16x8 sreg[JW];
  bf16x8 aC[MM], aN[MM];
  STAGE_LOAD(0, sreg);
  LDA(0, aC);
  STAGE_WRITE(0, sreg);
  __syncthreads();

  #pragma unroll 1
  for (int p=0; p<FULL; p++){
    int buf = p & 1;
    bool last = (p == FULL-1) && (REM == 0);
    if (!last) STAGE_LOAD(p+1, sreg);
    #pragma unroll
    for (int s=0;s<S;s++){
      int ks = p*S + s;
      int kn = ks + 1; if (kn > NSTEP-1) kn = NSTEP-1;
      LDA(kn, aN);
      COMPUTE(buf, s, aC);
      #pragma unroll
      for (int m=0;m<MM;m++) aC[m] = aN[m];
    }
    if (!last){ STAGE_WRITE(buf^1, sreg); __syncthreads(); }
  }
  if constexpr (REM > 0){
    constexpr int buf = FULL & 1;
    #pragma unroll
    for (int s=0;s<REM;s++){
      int ks = FULL*S + s;
      int kn = ks + 1; if (kn > NSTEP-1) kn = NSTEP-1;
      LDA(kn, aN);
      COMPUTE(buf, s, aC);
      #pragma unroll
      for (int m=0;m<MM;m++) aC[m] = aN[m];
    }
  }

  // ===== epilogue =====
  int bo = b + bo2;
  if constexpr (ACT == 0){
    __syncthreads();
    bf16* tile = reinterpret_cast<bf16*>(smem);
    #pragma unroll
    for (int n=0;n<NN;n++){
      int co = n*16 + (lane & 15);
      float bv = bias[co0 + co];
      #pragma unroll
      for (int m=0;m<MM;m++){
        #pragma unroll
        for (int r=0;r<4;r++){
          int pxl = w*(16*MM) + m*16 + (lane>>4)*4 + r;
          float v = fmaxf(acc[m][n][r] + bv, 0.0f);
          tile[pxl*CT + co] = __float2bfloat16(v);
        }
      }
    }
    __syncthreads();
    constexpr int NG16 = PXB*CT/8;
    #pragma unroll
    for (int j=0; j<(NG16+255)/256; j++){
      int g = t + j*256;
      if (NG16 >= 256*(j+1) || g < NG16){
        int f = g*8;
        int pxl = f / CT, c = f - pxl*CT;
        int ca = co0 + c;
        int cg = ca >> 5, cw = ca & 31;
        size_t dst = (((size_t)(b*CGO + cg)*HpO + (y+1))*WpO + (size_t)bx*PXB + 1 + pxl)*32 + cw;
        *reinterpret_cast<bf16x8*>(outP + dst) =
            *reinterpret_cast<const bf16x8*>(&tile[f]);
      }
    }
  } else {
    #pragma unroll
    for (int n=0;n<NN;n++){
      int co = co0 + n*16 + (lane & 15);
      float bv = (co < 3) ? bias[co] : 0.0f;
      #pragma unroll
      for (int m=0;m<MM;m++){
        #pragma unroll
        for (int r=0;r<4;r++){
          int px = px0 + m*16 + (lane>>4)*4 + r;
          float v = acc[m][n][r] + bv;
          if (ACT==1){
            if (co < 2)       out2[O_DG + (bo*2+co)*HW_ + y*W_ + px] = tanhf(v);
            else if (co == 2){
              float o = 1.0f/(1.0f+expf(-v));
              out2[O_O + bo*HW_ + y*W_ + px] = o;
              bf16x8 u;
              u[0] = f2bs(out2[O_IW + (bo*3+0)*HW_ + y*W_ + px]);
              u[1] = f2bs(out2[O_IW + (bo*3+1)*HW_ + y*W_ + px]);
              u[2] = f2bs(out2[O_IW + (bo*3+2)*HW_ + y*W_ + px]);
              u[3] = f2bs(out2[O_V + bo*HW_ + y*W_ + px]);
              u[4] = f2bs(o);
              u[5] = 0; u[6] = 0; u[7] = 0;
              *reinterpret_cast<bf16x8*>(xinU + (((bo*(H_+2) + y+1))*(W_+2) + px+1)*8) = u;
            }
          } else {
            if (co < 3)       out2[O_IT + (bo*3+co)*HW_ + y*W_ + px] = v;
          }
        }
      }
    }
  }
}

// ================= launch =================
extern "C" void kernel_launch(void* const* d_in, const int* in_sizes, int n_in,
                              void* d_out, int out_size, void* d_ws, size_t ws_size,
                              hipStream_t stream){
  const float* Is = (const float*)d_in[0];
  const float* Ds = (const float*)d_in[1];
  const float* Ks = (const float*)d_in[2];
  const float* Kt = (const float*)d_in[3];
  const float* dT = (const float*)d_in[4];
  const float* fw1=(const float*)d_in[5];  const float* fb1=(const float*)d_in[6];
  const float* fw2=(const float*)d_in[7];  const float* fb2=(const float*)d_in[8];
  const float* fw3=(const float*)d_in[9];  const float* fb3=(const float*)d_in[10];
  const float* we0=(const float*)d_in[11]; const float* be0=(const float*)d_in[12];
  const float* we1=(const float*)d_in[13]; const float* be1=(const float*)d_in[14];
  const float* we2=(const float*)d_in[15]; const float* be2=(const float*)d_in[16];
  const float* wd1=(const float*)d_in[17]; const float* bd1=(const float*)d_in[18];
  const float* wd0=(const float*)d_in[19]; const float* bd0=(const float*)d_in[20];
  const float* wo =(const float*)d_in[21]; const float* bo =(const float*)d_in[22];
  float* out = (float*)d_out;
  char* ws = (char*)d_ws;

  float*    kinv = (float*)(ws + WS_KINV);
  unsigned* zmax = (unsigned*)(ws + WS_ZMAX);
  unsigned* zbuf = (unsigned*)(ws + WS_ZBUF);
  float*    acc  = (float*)(ws + WS_ACC);
  bf16* xin = (bf16*)(ws + WS_XIN);
  bf16* h1  = (bf16*)(ws + WS_H1);
  bf16* h2  = (bf16*)(ws + WS_H2);
  bf16* e0  = (bf16*)(ws + WS_E0);
  bf16* e1  = (bf16*)(ws + WS_E1);
  bf16* e2  = (bf16*)(ws + WS_E2);
  bf16* d1  = (bf16*)(ws + WS_D1);
  bf16* d0h = (bf16*)(ws + WS_D0H);
  bf16* wtb = (bf16*)(ws + WS_WT);

  // ---- weight repack to fragment order ----
  k_wprep<5,8,32,32,1>    <<<12, 256, 0, stream>>>(fw1, wtb + WT_F1);
  k_wprep<32,32,32,32,1>  <<<48, 256, 0, stream>>>(fw2, wtb + WT_F2);
  k_wprep<32,32,3,16,1>   <<<24, 256, 0, stream>>>(fw3, wtb + WT_F3);
  k_wprep<5,8,32,32,1>    <<<12, 256, 0, stream>>>(we0, wtb + WT_E0);
  k_wprep<32,32,64,64,1>  <<<96, 256, 0, stream>>>(we1, wtb + WT_E1);
  k_wprep<64,64,128,64,2> <<<320,256, 0, stream>>>(we2, wtb + WT_E2);
  k_wprep<192,192,64,64,1><<<448,256, 0, stream>>>(wd1, wtb + WT_D1);
  k_wprep<96,96,32,32,1>  <<<112,256, 0, stream>>>(wd0, wtb + WT_D0);
  k_wprep<32,32,3,16,1>   <<<24, 256, 0, stream>>>(wo,  wtb + WT_O);

  // ---- splat ----
  hipMemsetAsync(zmax, 0, 32, stream);
  hipMemsetAsync(zbuf, 0x7f, 6291456, stream);
  hipMemsetAsync(acc, 0, 25165824, stream);
  k_mats<<<1, 64, 0, stream>>>(Ks, kinv);
  dim3 gpix(HW_/256, B_);
  k_proj<<<gpix, 256, 0, stream>>>(Ds, Kt, dT, kinv, zmax, zbuf, out);
  k_acc<<<gpix, 256, 0, stream>>>(Is, Ds, Kt, dT, kinv, (const float*)zbuf, zmax, acc);

  // halo totals (blocks of 256); blocked buffers: per-32ch group = extra batches
  const int hXIN = (8*1796*1 + 255)/256;
  const int hC32 = (8*1796*4 + 255)/256;
  const int hE1  = (16*900*4 + 255)/256;
  const int hE2  = (32*452*4 + 255)/256;
  const int hD1  = (16*900*4 + 255)/256;
  const int hD0H = (4*1796*4 + 255)/256;

  k_halo<8><<<hXIN, 256, 0, stream>>>(xin, H_+2, W_+2, 8);
  k_norm<<<gpix, 256, 0, stream>>>(acc, Is, Ds, out, xin);

  // ---- flow net ----
  k_halo<32><<<hC32, 256, 0, stream>>>(h1, H_+2, W_+2, 8);
  k_gconv<8,0,1,4,2,0,32, 2,384,8><<<2*384*8, 256, 0, stream>>>(
      xin, nullptr, wtb+WT_F1, fb1, h1, nullptr, nullptr, H_+2, W_+2, 0,0, H_+2, W_+2, 0);
  k_halo<32><<<hC32, 256, 0, stream>>>(h2, H_+2, W_+2, 8);
  k_gconv<32,0,1,4,2,0,32, 2,384,8><<<2*384*8, 256, 0, stream>>>(
      h1, nullptr, wtb+WT_F2, fb2, h2, nullptr, nullptr, H_+2, W_+2, 0,0, H_+2, W_+2, 0);
  k_gconv<32,0,1,4,1,1,16, 2,384,8><<<2*384*8, 256, 0, stream>>>(
      h2, nullptr, wtb+WT_F3, fb3, nullptr, out, xin, H_+2, W_+2, 0,0, 0,0, 0);

  // ---- unet encoder ----
  k_halo<32><<<hC32, 256, 0, stream>>>(e0, H_+2, W_+2, 8);
  k_gconv<8,0,1,4,2,0,32, 2,384,8><<<2*384*8, 256, 0, stream>>>(
      xin, nullptr, wtb+WT_E0, be0, e0, nullptr, nullptr, H_+2, W_+2, 0,0, H_+2, W_+2, 0);
  k_halo<32><<<hE1, 256, 0, stream>>>(e1, H2_+2, W2_+2, 16);
  k_gconv<32,0,2,4,4,0,64, 1,192,8><<<1*192*8, 256, 0, stream>>>(
      e0, nullptr, wtb+WT_E1, be1, e1, nullptr, nullptr, H_+2, W_+2, 0,0, H2_+2, W2_+2, 0);
  k_halo<32><<<hE2, 256, 0, stream>>>(e2, H4_+2, W4_+2, 32);
  k_gconv<64,0,2,2,4,0,128, 1,96,16><<<1*96*16, 256, 0, stream>>>(
      e1, nullptr, wtb+WT_E2, be2, e2, nullptr, nullptr, H2_+2, W2_+2, 0,0, H4_+2, W4_+2, 0);

  // ---- decoder: d1 full-batch, d0/out3 half-batch ----
  k_halo<32><<<hD1, 256, 0, stream>>>(d1, H2_+2, W2_+2, 16);
  k_gconv<192,128,1,4,4,0,64, 1,192,8><<<1*192*8, 256, 0, stream>>>(
      e1, e2, wtb+WT_D1, bd1, d1, nullptr, nullptr, H2_+2, W2_+2, H4_+2, W4_+2, H2_+2, W2_+2, 0);

  const size_t e0bStride = (size_t)(H_+2)*(W_+2)*32;
  const size_t d1bStride = (size_t)2*(H2_+2)*(W2_+2)*32;
  k_halo<32><<<hD0H, 256, 0, stream>>>(d0h, H_+2, W_+2, 4);
  for (int h = 0; h < 2; h++){
    const bf16* e0h = e0 + (size_t)h*4*e0bStride;
    const bf16* d1h = d1 + (size_t)h*4*d1bStride;
    k_gconv<96,64,1,4,2,0,32, 2,384,4><<<2*384*4, 256, 0, stream>>>(
        e0h, d1h, wtb+WT_D0, bd0, d0h, nullptr, nullptr, H_+2, W_+2, H2_+2, W2_+2, H_+2, W_+2, 0);
    k_gconv<32,0,1,4,1,2,16, 2,384,4><<<2*384*4, 256, 0, stream>>>(
        d0h, nullptr, wtb+WT_O, bo, nullptr, out, nullptr, H_+2, W_+2, 0,0, 0,0, h*4);
  }
}

// Round 19
// 959.560 us; speedup vs baseline: 1.0479x; 1.0479x over previous
//
#include <hip/hip_runtime.h>
#include <hip/hip_bf16.h>
#include <math.h>

using bf16 = __hip_bfloat16;
using bf16x8 = __attribute__((ext_vector_type(8))) short;
using f32x4  = __attribute__((ext_vector_type(4))) float;

#define B_ 8
#define H_ 384
#define W_ 512
#define HW_ (H_*W_)
#define H2_ 192
#define W2_ 256
#define H4_ 96
#define W4_ 128

#define TEMP_F 30.0f
#define HARD_Z_F 0.001f
#define EPS_F 1e-6f

// d_out element offsets (float32), in return order
#define O_IT 0
#define O_IW 4718592
#define O_V  9437184
#define O_O  11010048
#define O_GG 12582912
#define O_DG 15728640
#define O_ZT 18874368

// ---- workspace layout (bytes), lifetime-multiplexed ----
#define WS_ZBUF  0
#define WS_ACC   6291456           // accRG u32 (6.3MB) | accB u32 (6.3MB) | accW f32 (6.3MB)
#define WS_H1    0
#define WS_H2    101582848
#define WS_XIN   203165696
#define WS_E0    0
#define WS_E1    101582848
#define WS_E2    152836096
#define WS_D1    178927616
#define WS_D0H   101582848
#define WS_WT    230180864
#define WS_KINV  230742016
#define WS_ZMAX  230742528

// weight sub-offsets in ELEMENTS within WS_WT (fragment-order, padded K)
#define WT_F1 0
#define WT_F2 3072
#define WT_F3 15360
#define WT_E0 21504
#define WT_E1 24576
#define WT_E2 49152
#define WT_D1 131072
#define WT_D0 245760
#define WT_O  274432

static __device__ __forceinline__ short f2bs(float f){
  __hip_bfloat16 h = __float2bfloat16(f);
  return *reinterpret_cast<short*>(&h);
}
static __device__ __forceinline__ float bs2f(unsigned short s){
  __hip_bfloat16 h = *reinterpret_cast<__hip_bfloat16*>(&s);
  return __bfloat162float(h);
}
// packed bf16x2 atomic add (gfx940+ instruction, no return)
static __device__ __forceinline__ void atomic_pk_bf16(unsigned* addr, unsigned data){
  asm volatile("global_atomic_pk_add_bf16 %0, %1, off" :: "v"(addr), "v"(data) : "memory");
}

// S-chunk selection shared by wprep and gconv
template<int NSTEP> struct SSel {
  static constexpr int S = (NSTEP > 6) ? 4 : ((NSTEP > 3) ? 2 : 1);
  static constexpr int NSTEPP = ((NSTEP + S - 1)/S)*S;
};

// ================= splat =================
__global__ void k_mats(const float* __restrict__ Ks, float* __restrict__ kinv){
#pragma clang fp contract(off)
  int b = threadIdx.x;
  if (b >= B_) return;
  float A[3][3]; int piv[3] = {0,1,2};
  for (int k=0;k<3;k++) for (int j=0;j<3;j++) A[k][j] = Ks[b*9 + k*3 + j];
  for (int k=0;k<3;k++){
    int p = k; float mx = fabsf(A[k][k]);
    for (int i=k+1;i<3;i++){ float v = fabsf(A[i][k]); if (v > mx){ mx = v; p = i; } }
    if (p != k){
      for (int j=0;j<3;j++){ float t = A[k][j]; A[k][j] = A[p][j]; A[p][j] = t; }
      int t = piv[k]; piv[k] = piv[p]; piv[p] = t;
    }
    for (int i=k+1;i<3;i++){
      A[i][k] = A[i][k] / A[k][k];
      for (int j=k+1;j<3;j++) A[i][j] = A[i][j] - A[i][k]*A[k][j];
    }
  }
  for (int col=0; col<3; col++){
    float y0 = (piv[0]==col) ? 1.0f : 0.0f;
    float y1 = (piv[1]==col) ? 1.0f : 0.0f;
    float y2 = (piv[2]==col) ? 1.0f : 0.0f;
    y1 = y1 - A[1][0]*y0;
    y2 = (y2 - A[2][0]*y0) - A[2][1]*y1;
    float x2 = y2 / A[2][2];
    float x1 = (y1 - A[1][2]*x2) / A[1][1];
    float x0 = ((y0 - A[0][1]*x1) - A[0][2]*x2) / A[0][0];
    kinv[b*9 + 0*3 + col] = x0;
    kinv[b*9 + 1*3 + col] = x1;
    kinv[b*9 + 2*3 + col] = x2;
  }
}

__device__ __forceinline__ void proj_f(const float* __restrict__ Ki,
                                       const float* __restrict__ T,
                                       const float* __restrict__ Q,
                                       float d, float px, float py,
                                       float& xt, float& yt, float& z){
#pragma clang fp contract(off)
  float c0 = ((Ki[0]*px + Ki[1]*py) + Ki[2]) * d;
  float c1 = ((Ki[3]*px + Ki[4]*py) + Ki[5]) * d;
  float c2 = ((Ki[6]*px + Ki[7]*py) + Ki[8]) * d;
  float X0 = ((T[0]*c0 + T[1]*c1) + T[2]*c2) + T[3];
  float X1 = ((T[4]*c0 + T[5]*c1) + T[6]*c2) + T[7];
  float X2 = ((T[8]*c0 + T[9]*c1) + T[10]*c2) + T[11];
  float p0 = (Q[0]*X0 + Q[1]*X1) + Q[2]*X2;
  float p1 = (Q[3]*X0 + Q[4]*X1) + Q[5]*X2;
  float p2 = (Q[6]*X0 + Q[7]*X1) + Q[8]*X2;
  z = p2;
  float zc = fmaxf(z, EPS_F);
  xt = p0/zc; yt = p1/zc;
}

__global__ void k_proj(const float* __restrict__ Ds, const float* __restrict__ Kt,
                       const float* __restrict__ dT, const float* __restrict__ kinv,
                       unsigned* __restrict__ zmax,
                       unsigned* __restrict__ zbuf, float* __restrict__ out){
#pragma clang fp contract(off)
  int pix = blockIdx.x*256 + threadIdx.x;
  int b = blockIdx.y;
  int y = pix / W_, x = pix % W_;
  float d = fmaxf(__builtin_nontemporal_load(Ds + b*HW_ + pix), 0.001f);
  float xv, yv, z;
  proj_f(kinv + b*9, dT + b*16, Kt + b*9, d, (float)x, (float)y, xv, yv, z);
  int gi = b*HW_ + pix;
  __builtin_nontemporal_store((2.0f*xv + 1.0f)/(float)W_ - 1.0f, out + O_GG + 2*gi + 0);
  __builtin_nontemporal_store((2.0f*yv + 1.0f)/(float)H_ - 1.0f, out + O_GG + 2*gi + 1);
  __builtin_nontemporal_store(z, out + O_ZT + gi);
  float zi = (z > EPS_F) ? z : 0.0f;
  #pragma unroll
  for (int off=32; off; off>>=1) zi = fmaxf(zi, __shfl_down(zi, off, 64));
  __shared__ float sm[4];
  int lane = threadIdx.x & 63, wid = threadIdx.x >> 6;
  if (lane==0) sm[wid]=zi;
  __syncthreads();
  if (threadIdx.x==0){
    float m = fmaxf(fmaxf(sm[0],sm[1]), fmaxf(sm[2],sm[3]));
    atomicMax(zmax + b, __float_as_uint(m));
  }
  if (z > EPS_F){
    float x0 = floorf(xv), y0 = floorf(yv);
    unsigned zu = __float_as_uint(z);
    #pragma unroll
    for (int c=0;c<4;c++){
      float cx = x0 + (float)(c&1), cy = y0 + (float)(c>>1);
      float bw = (1.0f - fabsf(xv-cx)) * (1.0f - fabsf(yv-cy));
      if (cx>=0.f && cx<(float)W_ && cy>=0.f && cy<(float)H_ && bw>0.f){
        int flat = b*HW_ + (int)cy*W_ + (int)cx;
        atomicMin(zbuf + flat, zu);
      }
    }
  }
}

// acc: RG packed-bf16 plane + B packed-bf16 plane + den f32 plane (gating stays exact f32)
__global__ void k_acc(const float* __restrict__ Is, const float* __restrict__ Ds,
                      const float* __restrict__ Kt, const float* __restrict__ dT,
                      const float* __restrict__ kinv,
                      const float* __restrict__ zbuf,
                      const unsigned* __restrict__ zmax,
                      unsigned* __restrict__ accRG,
                      unsigned* __restrict__ accB,
                      float* __restrict__ accW){
#pragma clang fp contract(off)
  int pix = blockIdx.x*256+threadIdx.x;
  int b = blockIdx.y;
  int y = pix / W_, x = pix % W_;
  float d = fmaxf(__builtin_nontemporal_load(Ds + b*HW_ + pix), 0.001f);
  float xv, yv, z;
  proj_f(kinv + b*9, dT + b*16, Kt + b*9, d, (float)x, (float)y, xv, yv, z);
  if (!(z > EPS_F)) return;
  float zm = __uint_as_float(zmax[b]) + EPS_F;
  float q = z / zm;
  float w = expf((-TEMP_F) * q);
  float r  = __builtin_nontemporal_load(Is + (b*3+0)*HW_+pix);
  float g  = __builtin_nontemporal_load(Is + (b*3+1)*HW_+pix);
  float bl = __builtin_nontemporal_load(Is + (b*3+2)*HW_+pix);
  float x0 = floorf(xv), y0 = floorf(yv);
  #pragma unroll
  for (int c=0;c<4;c++){
    float cx = x0 + (float)(c&1), cy = y0 + (float)(c>>1);
    float bw = (1.0f - fabsf(xv-cx)) * (1.0f - fabsf(yv-cy));
    if (cx>=0.f && cx<(float)W_ && cy>=0.f && cy<(float)H_ && bw>0.f){
      int flat = b*HW_ + (int)cy*W_ + (int)cx;
      if (z <= zbuf[flat] + HARD_Z_F){
        float wt = bw*w;
        unsigned rg = (unsigned)(unsigned short)f2bs(wt*r)
                    | ((unsigned)(unsigned short)f2bs(wt*g) << 16);
        atomic_pk_bf16(accRG + flat, rg);
        unsigned bb = (unsigned)(unsigned short)f2bs(wt*bl);
        atomic_pk_bf16(accB + flat, bb);
        atomicAdd(accW + flat, wt);
      }
    }
  }
}

// k_norm + fused flow-net input pack
__global__ void k_norm(const unsigned* __restrict__ accRG,
                       const unsigned* __restrict__ accB,
                       const float* __restrict__ accW,
                       const float* __restrict__ Is,
                       const float* __restrict__ Ds, float* __restrict__ out,
                       bf16* __restrict__ xin){
#pragma clang fp contract(off)
  int pix = blockIdx.x*256+threadIdx.x;
  int b = blockIdx.y;
  int y = pix / W_, x = pix % W_;
  int gi = b*HW_+pix;
  unsigned rg = __builtin_nontemporal_load(accRG + gi);
  unsigned bb = __builtin_nontemporal_load(accB + gi);
  float nx = bs2f((unsigned short)(rg & 0xffffu));
  float ny = bs2f((unsigned short)(rg >> 16));
  float nz = bs2f((unsigned short)(bb & 0xffffu));
  float den = __builtin_nontemporal_load(accW + gi);
  float denc = fmaxf(den, EPS_F);
  bool on = den > EPS_F;
  float V = fminf(fmaxf(den, 0.0f), 1.0f);
  float i0 = __builtin_nontemporal_load(Is + (b*3+0)*HW_+pix);
  float i1 = __builtin_nontemporal_load(Is + (b*3+1)*HW_+pix);
  float i2 = __builtin_nontemporal_load(Is + (b*3+2)*HW_+pix);
  float dv = __builtin_nontemporal_load(Ds + gi);
  __builtin_nontemporal_store(on ? nx/denc : 0.0f, out + O_IW + (b*3+0)*HW_+pix);
  __builtin_nontemporal_store(on ? ny/denc : 0.0f, out + O_IW + (b*3+1)*HW_+pix);
  __builtin_nontemporal_store(on ? nz/denc : 0.0f, out + O_IW + (b*3+2)*HW_+pix);
  __builtin_nontemporal_store(V, out + O_V + gi);
  bf16x8 v;
  v[0] = f2bs(i0);
  v[1] = f2bs(i1);
  v[2] = f2bs(i2);
  v[3] = f2bs(dv);
  v[4] = f2bs(V);
  v[5] = 0; v[6] = 0; v[7] = 0;
  *reinterpret_cast<bf16x8*>(xin + (((b*(H_+2) + y+1))*(W_+2) + x+1)*8) = v;
}

// halo zeroing: border ring of a padded NHWC/blocked buffer (per 32/8-ch group)
template<int C>
__global__ void k_halo(bf16* __restrict__ buf, int Hp, int Wp, int nb){
  int nh = 2*Wp + 2*(Hp-2);
  int i = blockIdx.x*256 + threadIdx.x;
  int total = nb*nh*(C/8);
  if (i >= total) return;
  int cv = i % (C/8); int hp = (i / (C/8)) % nh; int b = i / ((C/8)*nh);
  int y, x;
  if (hp < Wp){ y = 0; x = hp; }
  else if (hp < 2*Wp){ y = Hp-1; x = hp - Wp; }
  else { int r = hp - 2*Wp; y = 1 + (r>>1); x = (r&1) ? Wp-1 : 0; }
  bf16x8 zv = {0,0,0,0,0,0,0,0};
  *reinterpret_cast<bf16x8*>(buf + (((size_t)b*Hp + y)*Wp + x)*C + cv*8) = zv;
}

// ======== weight repack -> MFMA FRAGMENT ORDER in global memory ========
template<int CIN, int CPAD, int COUT, int CT, int NCO>
__global__ void k_wprep(const float* __restrict__ src, bf16* __restrict__ dst){
  constexpr int KP = ((9*CPAD + 31)/32)*32;
  constexpr int NSTEP = KP/32;
  constexpr int NSTEPP = SSel<NSTEP>::NSTEPP;
  constexpr int NN = CT/16;
  int i = blockIdx.x*256 + threadIdx.x;
  if (i >= NCO*NSTEPP*NN*512) return;
  int e8 = i & 7;
  int g = i >> 3;
  int l = g & 63;
  int rest = g >> 6;
  int n = rest % NN;
  int rest2 = rest / NN;
  int ks = rest2 % NSTEPP;
  int cog = rest2 / NSTEPP;
  int co = cog*CT + n*16 + (l & 15);
  int k = ks*32 + (l >> 4)*8 + e8;
  int tap = k / CPAD, c = k - tap*CPAD;
  float v = 0.0f;
  if (co < COUT && tap < 9 && c < CIN)
    v = src[((co*CIN + c)*3 + tap/3)*3 + (tap%3)];
  dst[i] = __float2bfloat16(v);
}

// ===== MFMA implicit-GEMM 3x3 conv: channel-blocked activations (coalesced A) =====
// Activations with C>32 are stored [b][cg][Hp][Wp][32]; C<=32 is the CG=1 case.
// ACT: 0 = ReLU -> bf16 outP (blocked tiled store); 1 = flow head (+unet pack); 2 = IT head
template<int CPAD, int CA, int STRIDE, int MM, int NN, int ACT, int COUT,
         int GX, int GY, int GZ>
__global__ __launch_bounds__(256) void k_gconv(
    const bf16* __restrict__ inB, const bf16* __restrict__ inA,
    const bf16* __restrict__ wt, const float* __restrict__ bias,
    bf16* __restrict__ outP, float* __restrict__ out2, bf16* __restrict__ xinU,
    int HpB, int WpB, int HpA, int WpA, int HpO, int WpO, int bo2)
{
  constexpr int CB = CPAD - CA;
  constexpr int CGB = (CB >= 32) ? CB/32 : 1;
  constexpr int CGA = (CA >= 32) ? CA/32 : 1;
  constexpr int CGO = (COUT >= 32) ? COUT/32 : 1;
  constexpr int KP = ((9*CPAD + 31)/32)*32;
  constexpr int NSTEP = KP/32;
  constexpr int CT = 16*NN;
  constexpr int NCO = COUT/CT;
  constexpr int S = SSel<NSTEP>::S;
  constexpr int NSTEPP = SSel<NSTEP>::NSTEPP;
  constexpr int FULL = NSTEP / S;
  constexpr int REM  = NSTEP % S;
  constexpr int NGRAN = S*NN*64;
  constexpr int JW = (NGRAN + 255)/256;
  constexpr int PIPES = NGRAN*8;
  constexpr int PXB = 64*MM;
  constexpr int PIPEB = 2*PIPES*2;
  constexpr int TILEB = (ACT==0) ? PXB*CT*2 : 0;
  constexpr int MAXB = (PIPEB > TILEB) ? PIPEB : TILEB;
  __shared__ __align__(16) char smem[MAXB];
  short* ldsS = reinterpret_cast<short*>(smem);

  // XCD-chunked bijective swizzle
  constexpr int NWG = GX*GY*GZ;
  constexpr int Q = NWG/8, R = NWG%8;
  int orig = blockIdx.x;
  int xcd = orig & 7, idx = orig >> 3;
  int wg = (xcd < R ? xcd*(Q+1) : R*(Q+1) + (xcd-R)*Q) + idx;
  int bx = wg % GX;
  int by = (wg / GX) % GY;
  int bz = wg / (GX*GY);

  int lane = threadIdx.x & 63;
  int w = threadIdx.x >> 6;
  int arow = lane & 15, kg = lane >> 4;
  int y = by;
  int b = bz / NCO;
  int co0 = (bz - b*NCO) * CT;
  int px0 = bx*PXB + w*(16*MM);
  int t = threadIdx.x;
  const bf16* wgbase = wt + (size_t)(co0/CT)*NSTEPP*NN*512;

  f32x4 acc[MM][NN];
  #pragma unroll
  for (int m=0;m<MM;m++)
    #pragma unroll
    for (int n=0;n<NN;n++) acc[m][n] = (f32x4){0.f,0.f,0.f,0.f};

  // per-lane invariant offsets for A (blocked: 32ch inner)
  int laneB[MM];
  int lamA[MM][3];
  #pragma unroll
  for (int m=0;m<MM;m++){
    int px = px0 + m*16 + arow;
    laneB[m] = (STRIDE==1 ? px : 2*px)*32 + kg*8;
    if constexpr (CA > 0){
      #pragma unroll
      for (int kx=0;kx<3;kx++)
        lamA[m][kx] = (((px + kx - 1) >> 1) + 1)*32 + kg*8;
    }
  }

  auto LDA = [&](int ks, bf16x8 (&a)[MM]) {
    if constexpr (CPAD >= 32){
      int kk0 = ks*32;
      int tap = kk0 / CPAD;
      int c0 = kk0 - tap*CPAD;
      int kyy = tap/3, kx = tap - kyy*3;
      bool isA = false;
      if constexpr (CA > 0) isA = (c0 < CA);
      if (isA){
        if constexpr (CA > 0){
          int cga = c0 >> 5;
          int yu = ((y + kyy - 1) >> 1) + 1;
          int sA = ((b*CGA + cga)*HpA + yu)*WpA*32;
          #pragma unroll
          for (int m=0;m<MM;m++){
            int la = (kx==0) ? lamA[m][0] : ((kx==1) ? lamA[m][1] : lamA[m][2]);
            a[m] = *reinterpret_cast<const bf16x8*>(inA + sA + la);
          }
        }
      } else {
        int cgb = (c0 - CA) >> 5;
        int sB = (STRIDE==1)
          ? (((b*CGB + cgb)*HpB + y + kyy)*WpB + kx)*32
          : (((b*CGB + cgb)*HpB + 2*y + kyy + 1)*WpB + kx + 1)*32;
        #pragma unroll
        for (int m=0;m<MM;m++)
          a[m] = *reinterpret_cast<const bf16x8*>(inB + sB + laneB[m]);
      }
    } else {
      int k = ks*32 + kg*8;
      int tap = k >> 3;
      if (tap >= 9) tap = 0;
      int kyy = tap/3, kx = tap - (tap/3)*3;
      #pragma unroll
      for (int m=0;m<MM;m++){
        int px = px0 + m*16 + arow;
        a[m] = *reinterpret_cast<const bf16x8*>(inB + ((b*HpB + y + kyy)*WpB + px + kx)*8);
      }
    }
  };

  auto STAGE_LOAD = [&](int p, bf16x8 (&sreg)[JW]){
    const bf16* g = wgbase + (size_t)p*NGRAN*8;
    #pragma unroll
    for (int j=0;j<JW;j++){
      int e = t + j*256;
      if (NGRAN >= 256*(j+1) || e < NGRAN)
        sreg[j] = *reinterpret_cast<const bf16x8*>(g + e*8);
    }
  };
  auto STAGE_WRITE = [&](int buf, bf16x8 (&sreg)[JW]){
    #pragma unroll
    for (int j=0;j<JW;j++){
      int e = t + j*256;
      if (NGRAN >= 256*(j+1) || e < NGRAN)
        *reinterpret_cast<bf16x8*>(&ldsS[buf*PIPES + e*8]) = sreg[j];
    }
  };

  auto COMPUTE = [&](int buf, int s, bf16x8 (&a)[MM]){
    bf16x8 bb[NN];
    #pragma unroll
    for (int n=0;n<NN;n++)
      bb[n] = *reinterpret_cast<const bf16x8*>(&ldsS[buf*PIPES + ((s*NN + n)*64 + lane)*8]);
    #pragma unroll
    for (int m=0;m<MM;m++)
      #pragma unroll
      for (int n=0;n<NN;n++)
        acc[m][n] = __builtin_amdgcn_mfma_f32_16x16x32_bf16(a[m], bb[n], acc[m][n], 0,0,0);
  };

  bf16x8 sreg[JW];
  bf16x8 aC[MM], aN[MM];
  STAGE_LOAD(0, sreg);
  LDA(0, aC);
  STAGE_WRITE(0, sreg);
  __syncthreads();

  #pragma unroll 1
  for (int p=0; p<FULL; p++){
    int buf = p & 1;
    bool last = (p == FULL-1) && (REM == 0);
    if (!last) STAGE_LOAD(p+1, sreg);
    #pragma unroll
    for (int s=0;s<S;s++){
      int ks = p*S + s;
      int kn = ks + 1; if (kn > NSTEP-1) kn = NSTEP-1;
      LDA(kn, aN);
      COMPUTE(buf, s, aC);
      #pragma unroll
      for (int m=0;m<MM;m++) aC[m] = aN[m];
    }
    if (!last){ STAGE_WRITE(buf^1, sreg); __syncthreads(); }
  }
  if constexpr (REM > 0){
    constexpr int buf = FULL & 1;
    #pragma unroll
    for (int s=0;s<REM;s++){
      int ks = FULL*S + s;
      int kn = ks + 1; if (kn > NSTEP-1) kn = NSTEP-1;
      LDA(kn, aN);
      COMPUTE(buf, s, aC);
      #pragma unroll
      for (int m=0;m<MM;m++) aC[m] = aN[m];
    }
  }

  // ===== epilogue =====
  int bo = b + bo2;
  if constexpr (ACT == 0){
    __syncthreads();
    bf16* tile = reinterpret_cast<bf16*>(smem);
    #pragma unroll
    for (int n=0;n<NN;n++){
      int co = n*16 + (lane & 15);
      float bv = bias[co0 + co];
      #pragma unroll
      for (int m=0;m<MM;m++){
        #pragma unroll
        for (int r=0;r<4;r++){
          int pxl = w*(16*MM) + m*16 + (lane>>4)*4 + r;
          float v = fmaxf(acc[m][n][r] + bv, 0.0f);
          tile[pxl*CT + co] = __float2bfloat16(v);
        }
      }
    }
    __syncthreads();
    constexpr int NG16 = PXB*CT/8;
    #pragma unroll
    for (int j=0; j<(NG16+255)/256; j++){
      int g = t + j*256;
      if (NG16 >= 256*(j+1) || g < NG16){
        int f = g*8;
        int pxl = f / CT, c = f - pxl*CT;
        int ca = co0 + c;
        int cg = ca >> 5, cw = ca & 31;
        size_t dst = (((size_t)(b*CGO + cg)*HpO + (y+1))*WpO + (size_t)bx*PXB + 1 + pxl)*32 + cw;
        *reinterpret_cast<bf16x8*>(outP + dst) =
            *reinterpret_cast<const bf16x8*>(&tile[f]);
      }
    }
  } else {
    #pragma unroll
    for (int n=0;n<NN;n++){
      int co = co0 + n*16 + (lane & 15);
      float bv = (co < 3) ? bias[co] : 0.0f;
      #pragma unroll
      for (int m=0;m<MM;m++){
        #pragma unroll
        for (int r=0;r<4;r++){
          int px = px0 + m*16 + (lane>>4)*4 + r;
          float v = acc[m][n][r] + bv;
          if (ACT==1){
            if (co < 2)       out2[O_DG + (bo*2+co)*HW_ + y*W_ + px] = tanhf(v);
            else if (co == 2){
              float o = 1.0f/(1.0f+expf(-v));
              out2[O_O + bo*HW_ + y*W_ + px] = o;
              bf16x8 u;
              u[0] = f2bs(out2[O_IW + (bo*3+0)*HW_ + y*W_ + px]);
              u[1] = f2bs(out2[O_IW + (bo*3+1)*HW_ + y*W_ + px]);
              u[2] = f2bs(out2[O_IW + (bo*3+2)*HW_ + y*W_ + px]);
              u[3] = f2bs(out2[O_V + bo*HW_ + y*W_ + px]);
              u[4] = f2bs(o);
              u[5] = 0; u[6] = 0; u[7] = 0;
              *reinterpret_cast<bf16x8*>(xinU + (((bo*(H_+2) + y+1))*(W_+2) + px+1)*8) = u;
            }
          } else {
            if (co < 3)       out2[O_IT + (bo*3+co)*HW_ + y*W_ + px] = v;
          }
        }
      }
    }
  }
}

// ================= launch =================
extern "C" void kernel_launch(void* const* d_in, const int* in_sizes, int n_in,
                              void* d_out, int out_size, void* d_ws, size_t ws_size,
                              hipStream_t stream){
  const float* Is = (const float*)d_in[0];
  const float* Ds = (const float*)d_in[1];
  const float* Ks = (const float*)d_in[2];
  const float* Kt = (const float*)d_in[3];
  const float* dT = (const float*)d_in[4];
  const float* fw1=(const float*)d_in[5];  const float* fb1=(const float*)d_in[6];
  const float* fw2=(const float*)d_in[7];  const float* fb2=(const float*)d_in[8];
  const float* fw3=(const float*)d_in[9];  const float* fb3=(const float*)d_in[10];
  const float* we0=(const float*)d_in[11]; const float* be0=(const float*)d_in[12];
  const float* we1=(const float*)d_in[13]; const float* be1=(const float*)d_in[14];
  const float* we2=(const float*)d_in[15]; const float* be2=(const float*)d_in[16];
  const float* wd1=(const float*)d_in[17]; const float* bd1=(const float*)d_in[18];
  const float* wd0=(const float*)d_in[19]; const float* bd0=(const float*)d_in[20];
  const float* wo =(const float*)d_in[21]; const float* bo =(const float*)d_in[22];
  float* out = (float*)d_out;
  char* ws = (char*)d_ws;

  float*    kinv = (float*)(ws + WS_KINV);
  unsigned* zmax = (unsigned*)(ws + WS_ZMAX);
  unsigned* zbuf = (unsigned*)(ws + WS_ZBUF);
  unsigned* accRG = (unsigned*)(ws + WS_ACC);
  unsigned* accB  = (unsigned*)(ws + WS_ACC + 6291456);
  float*    accW  = (float*)(ws + WS_ACC + 12582912);
  bf16* xin = (bf16*)(ws + WS_XIN);
  bf16* h1  = (bf16*)(ws + WS_H1);
  bf16* h2  = (bf16*)(ws + WS_H2);
  bf16* e0  = (bf16*)(ws + WS_E0);
  bf16* e1  = (bf16*)(ws + WS_E1);
  bf16* e2  = (bf16*)(ws + WS_E2);
  bf16* d1  = (bf16*)(ws + WS_D1);
  bf16* d0h = (bf16*)(ws + WS_D0H);
  bf16* wtb = (bf16*)(ws + WS_WT);

  // ---- weight repack to fragment order ----
  k_wprep<5,8,32,32,1>    <<<12, 256, 0, stream>>>(fw1, wtb + WT_F1);
  k_wprep<32,32,32,32,1>  <<<48, 256, 0, stream>>>(fw2, wtb + WT_F2);
  k_wprep<32,32,3,16,1>   <<<24, 256, 0, stream>>>(fw3, wtb + WT_F3);
  k_wprep<5,8,32,32,1>    <<<12, 256, 0, stream>>>(we0, wtb + WT_E0);
  k_wprep<32,32,64,64,1>  <<<96, 256, 0, stream>>>(we1, wtb + WT_E1);
  k_wprep<64,64,128,64,2> <<<320,256, 0, stream>>>(we2, wtb + WT_E2);
  k_wprep<192,192,64,64,1><<<448,256, 0, stream>>>(wd1, wtb + WT_D1);
  k_wprep<96,96,32,32,1>  <<<112,256, 0, stream>>>(wd0, wtb + WT_D0);
  k_wprep<32,32,3,16,1>   <<<24, 256, 0, stream>>>(wo,  wtb + WT_O);

  // ---- splat ----
  hipMemsetAsync(zmax, 0, 32, stream);
  hipMemsetAsync(zbuf, 0x7f, 6291456, stream);
  hipMemsetAsync(accRG, 0, 18874368, stream);   // RG + B + W planes
  k_mats<<<1, 64, 0, stream>>>(Ks, kinv);
  dim3 gpix(HW_/256, B_);
  k_proj<<<gpix, 256, 0, stream>>>(Ds, Kt, dT, kinv, zmax, zbuf, out);
  k_acc<<<gpix, 256, 0, stream>>>(Is, Ds, Kt, dT, kinv, (const float*)zbuf, zmax, accRG, accB, accW);

  // halo totals (blocks of 256); blocked buffers: per-32ch group = extra batches
  const int hXIN = (8*1796*1 + 255)/256;
  const int hC32 = (8*1796*4 + 255)/256;
  const int hE1  = (16*900*4 + 255)/256;
  const int hE2  = (32*452*4 + 255)/256;
  const int hD1  = (16*900*4 + 255)/256;
  const int hD0H = (4*1796*4 + 255)/256;

  k_halo<8><<<hXIN, 256, 0, stream>>>(xin, H_+2, W_+2, 8);
  k_norm<<<gpix, 256, 0, stream>>>(accRG, accB, accW, Is, Ds, out, xin);

  // ---- flow net ----
  k_halo<32><<<hC32, 256, 0, stream>>>(h1, H_+2, W_+2, 8);
  k_gconv<8,0,1,4,2,0,32, 2,384,8><<<2*384*8, 256, 0, stream>>>(
      xin, nullptr, wtb+WT_F1, fb1, h1, nullptr, nullptr, H_+2, W_+2, 0,0, H_+2, W_+2, 0);
  k_halo<32><<<hC32, 256, 0, stream>>>(h2, H_+2, W_+2, 8);
  k_gconv<32,0,1,4,2,0,32, 2,384,8><<<2*384*8, 256, 0, stream>>>(
      h1, nullptr, wtb+WT_F2, fb2, h2, nullptr, nullptr, H_+2, W_+2, 0,0, H_+2, W_+2, 0);
  k_gconv<32,0,1,4,1,1,16, 2,384,8><<<2*384*8, 256, 0, stream>>>(
      h2, nullptr, wtb+WT_F3, fb3, nullptr, out, xin, H_+2, W_+2, 0,0, 0,0, 0);

  // ---- unet encoder ----
  k_halo<32><<<hC32, 256, 0, stream>>>(e0, H_+2, W_+2, 8);
  k_gconv<8,0,1,4,2,0,32, 2,384,8><<<2*384*8, 256, 0, stream>>>(
      xin, nullptr, wtb+WT_E0, be0, e0, nullptr, nullptr, H_+2, W_+2, 0,0, H_+2, W_+2, 0);
  k_halo<32><<<hE1, 256, 0, stream>>>(e1, H2_+2, W2_+2, 16);
  k_gconv<32,0,2,4,4,0,64, 1,192,8><<<1*192*8, 256, 0, stream>>>(
      e0, nullptr, wtb+WT_E1, be1, e1, nullptr, nullptr, H_+2, W_+2, 0,0, H2_+2, W2_+2, 0);
  k_halo<32><<<hE2, 256, 0, stream>>>(e2, H4_+2, W4_+2, 32);
  k_gconv<64,0,2,2,4,0,128, 1,96,16><<<1*96*16, 256, 0, stream>>>(
      e1, nullptr, wtb+WT_E2, be2, e2, nullptr, nullptr, H2_+2, W2_+2, 0,0, H4_+2, W4_+2, 0);

  // ---- decoder: d1 full-batch, d0/out3 half-batch ----
  k_halo<32><<<hD1, 256, 0, stream>>>(d1, H2_+2, W2_+2, 16);
  k_gconv<192,128,1,4,4,0,64, 1,192,8><<<1*192*8, 256, 0, stream>>>(
      e1, e2, wtb+WT_D1, bd1, d1, nullptr, nullptr, H2_+2, W2_+2, H4_+2, W4_+2, H2_+2, W2_+2, 0);

  const size_t e0bStride = (size_t)(H_+2)*(W_+2)*32;
  const size_t d1bStride = (size_t)2*(H2_+2)*(W2_+2)*32;
  k_halo<32><<<hD0H, 256, 0, stream>>>(d0h, H_+2, W_+2, 4);
  for (int h = 0; h < 2; h++){
    const bf16* e0h = e0 + (size_t)h*4*e0bStride;
    const bf16* d1h = d1 + (size_t)h*4*d1bStride;
    k_gconv<96,64,1,4,2,0,32, 2,384,4><<<2*384*4, 256, 0, stream>>>(
        e0h, d1h, wtb+WT_D0, bd0, d0h, nullptr, nullptr, H_+2, W_+2, H2_+2, W2_+2, H_+2, W_+2, 0);
    k_gconv<32,0,1,4,1,2,16, 2,384,4><<<2*384*4, 256, 0, stream>>>(
        d0h, nullptr, wtb+WT_O, bo, nullptr, out, nullptr, H_+2, W_+2, 0,0, 0,0, h*4);
  }
}